// Round 1
// baseline (268.012 us; speedup 1.0000x reference)
//
#include <hip/hip_runtime.h>
#include <hip/hip_bf16.h>
#include <type_traits>
#include <utility>

// Problem: B=32, P=4, N=1024, C=384.
// softmax over a size-1 axis == 1.0, so:
//   cv[b,p,:]  = (sum_n x[b,p,n,:]) @ Wk + N*bk          (fp32, exact)
//   out        = (relu(x@Wv + bv) * cv) @ Wp + bp        (bf16 MFMA, fused)
#define C_    384
#define N_    1024
#define G_    128          // B*P groups
#define QKVD  769
#define SPLIT 16           // xsum row-split per group

typedef float  f32x4 __attribute__((ext_vector_type(4)));
typedef short  s16x8 __attribute__((ext_vector_type(8)));
typedef __bf16 b16x8 __attribute__((ext_vector_type(8)));

// The gfx950 bf16 mfma builtin takes either v8i16 or v8bf16 depending on the
// toolchain; select whichever signature type-checks.
template <typename V, typename = void>
struct mfma_takes : std::false_type {};
template <typename V>
struct mfma_takes<V, std::void_t<decltype(__builtin_amdgcn_mfma_f32_16x16x32_bf16(
    std::declval<V>(), std::declval<V>(), std::declval<f32x4>(), 0, 0, 0))>>
    : std::true_type {};

using frag_t = std::conditional_t<mfma_takes<s16x8>::value, s16x8, b16x8>;

template <typename V>
__device__ __forceinline__ f32x4 mfma_bf16(V a, V b, f32x4 c) {
  return __builtin_amdgcn_mfma_f32_16x16x32_bf16(a, b, c, 0, 0, 0);
}

__device__ __forceinline__ unsigned short f2bf(float f) {
  union { float f; unsigned u; } v; v.f = f;
  unsigned r = v.u + 0x7fffu + ((v.u >> 16) & 1u);   // RNE
  return (unsigned short)(r >> 16);
}

// ---------------- K1: xsum[g][c] = sum_n x[g*1024+n][c] ----------------
__global__ void k_xsum(const float* __restrict__ x, float* __restrict__ xsum) {
  int g = blockIdx.x >> 4;         // /SPLIT
  int s = blockIdx.x & (SPLIT - 1);
  int c = threadIdx.x;             // 384 threads
  const float* p = x + ((size_t)g * N_ + (size_t)s * (N_ / SPLIT)) * C_ + c;
  float acc = 0.f;
#pragma unroll 8
  for (int r = 0; r < N_ / SPLIT; ++r) acc += p[(size_t)r * C_];
  atomicAdd(&xsum[g * C_ + c], acc);
}

// ---------------- K2: cv[g][c] = xsum[g]@Wk[:,c] + N*bk[c] ----------------
__global__ void k_cv(const float* __restrict__ xsum, const float* __restrict__ w_qkv,
                     const float* __restrict__ b_qkv, float* __restrict__ cv) {
  __shared__ float xs[C_];
  int g = blockIdx.x, c = threadIdx.x;   // 384 threads
  xs[c] = xsum[g * C_ + c];
  __syncthreads();
  float acc = 0.f;
#pragma unroll 4
  for (int k = 0; k < C_; ++k) acc += xs[k] * w_qkv[k * QKVD + 1 + c];
  cv[g * C_ + c] = acc + (float)N_ * b_qkv[1 + c];
}

// ------- K3: pack Wv (w_qkv[:,385:769]) and Wp (w_proj) as bf16 frag-major -------
// layout: entry (kk,nf,lane) -> 8 bf16 (B[k=kk*32+(lane>>4)*8 + j][n=nf*16+(lane&15)])
__global__ void k_pack(const float* __restrict__ w_qkv, const float* __restrict__ w_proj,
                       unsigned short* __restrict__ pWv, unsigned short* __restrict__ pWp) {
  int bid = blockIdx.x;
  int mat = bid / 288;             // 0: Wv, 1: Wp    (288 = 12 kk * 24 nf)
  int r   = bid % 288;
  int kk = r / 24, nf = r % 24;
  int lane = threadIdx.x;          // 64
  int kbase = kk * 32 + (lane >> 4) * 8;
  int n = nf * 16 + (lane & 15);
  unsigned v[4];
#pragma unroll
  for (int jj = 0; jj < 4; ++jj) {
    int k0 = kbase + jj * 2;
    float f0 = mat ? w_proj[(size_t)k0 * C_ + n]       : w_qkv[(size_t)k0 * QKVD + 385 + n];
    float f1 = mat ? w_proj[(size_t)(k0 + 1) * C_ + n] : w_qkv[(size_t)(k0 + 1) * QKVD + 385 + n];
    v[jj] = (unsigned)f2bf(f0) | ((unsigned)f2bf(f1) << 16);
  }
  unsigned short* dst = (mat ? pWp : pWv) + ((size_t)r * 64 + lane) * 8;
  uint4 w; w.x = v[0]; w.y = v[1]; w.z = v[2]; w.w = v[3];
  *(uint4*)dst = w;
}

// ---------------- K4: fused value-GEMM -> relu*cv -> proj-GEMM ----------------
// block: 256 thr (4 waves), 64 rows x full 384 cols; wave w owns cols [w*96, w*96+96)
__global__ __launch_bounds__(256) void k_fused(
    const float* __restrict__ x, const unsigned short* __restrict__ pWv,
    const unsigned short* __restrict__ pWp, const float* __restrict__ cv,
    const float* __restrict__ b_qkv, const float* __restrict__ b_proj,
    float* __restrict__ out) {
  __shared__ __align__(16) char tile[64 * 768];   // 64 x 384 bf16, XOR-swizzled
  __shared__ float cv_l[C_], bv_l[C_], bp_l[C_];

  const int tid  = threadIdx.x;
  const int lane = tid & 63;
  const int wv   = tid >> 6;
  const int R0   = blockIdx.x * 64;
  const int g    = R0 >> 10;

  for (int c = tid; c < C_; c += 256) {
    cv_l[c] = cv[g * C_ + c];
    bv_l[c] = b_qkv[1 + C_ + c];
    bp_l[c] = b_proj[c];
  }

  // stage x tile fp32 -> bf16 -> LDS (swizzle: byte ^= (row&7)<<4, row stride 768B)
  {
    const float* xg = x + (size_t)R0 * C_;
#pragma unroll
    for (int i = 0; i < 12; ++i) {
      int ch  = i * 256 + tid;        // 3072 chunks of 8 elems
      int row = ch / 48;
      int col = (ch % 48) * 8;
      const float4* s0 = (const float4*)(xg + (size_t)row * C_ + col);
      float4 a = s0[0], b = s0[1];
      uint4 w;
      w.x = (unsigned)f2bf(a.x) | ((unsigned)f2bf(a.y) << 16);
      w.y = (unsigned)f2bf(a.z) | ((unsigned)f2bf(a.w) << 16);
      w.z = (unsigned)f2bf(b.x) | ((unsigned)f2bf(b.y) << 16);
      w.w = (unsigned)f2bf(b.z) | ((unsigned)f2bf(b.w) << 16);
      int byte = row * 768 + col * 2;
      byte ^= (row & 7) << 4;
      *(uint4*)(tile + byte) = w;
    }
  }
  __syncthreads();

  const int wcol = wv * 96;
  const f32x4 zero = {0.f, 0.f, 0.f, 0.f};
  f32x4 acc[4][6];
#pragma unroll
  for (int m = 0; m < 4; ++m)
#pragma unroll
    for (int n = 0; n < 6; ++n) acc[m][n] = zero;

  // GEMM1: value = x @ Wv
  for (int kk = 0; kk < 12; ++kk) {
    frag_t A[4], Bv[6];
    int kb2 = (kk * 32 + (lane >> 4) * 8) * 2;
#pragma unroll
    for (int m = 0; m < 4; ++m) {
      int row = m * 16 + (lane & 15);
      int byte = row * 768 + kb2;
      byte ^= (row & 7) << 4;
      A[m] = *(const frag_t*)(tile + byte);
    }
    const unsigned short* bp_ = pWv + ((size_t)(kk * 24 + wv * 6) * 64 + lane) * 8;
#pragma unroll
    for (int n = 0; n < 6; ++n) Bv[n] = *(const frag_t*)(bp_ + (size_t)n * 64 * 8);
#pragma unroll
    for (int m = 0; m < 4; ++m)
#pragma unroll
      for (int n = 0; n < 6; ++n) acc[m][n] = mfma_bf16(A[m], Bv[n], acc[m][n]);
  }

  __syncthreads();   // all waves done reading x tile

  // epilogue1: gated = relu(value + bv) * cv  -> bf16 -> same LDS tile
#pragma unroll
  for (int m = 0; m < 4; ++m) {
#pragma unroll
    for (int n = 0; n < 6; ++n) {
      int col = wcol + n * 16 + (lane & 15);
      float cvv = cv_l[col], bvv = bv_l[col];
#pragma unroll
      for (int r = 0; r < 4; ++r) {
        int row = m * 16 + (lane >> 4) * 4 + r;   // verified C/D layout
        float val = acc[m][n][r] + bvv;
        val = fmaxf(val, 0.f) * cvv;
        int byte = row * 768 + col * 2;
        byte ^= (row & 7) << 4;
        *(unsigned short*)(tile + byte) = f2bf(val);
      }
    }
  }
  __syncthreads();   // gated tile complete

  // GEMM2: out = gated @ Wp
  f32x4 acc2[4][6];
#pragma unroll
  for (int m = 0; m < 4; ++m)
#pragma unroll
    for (int n = 0; n < 6; ++n) acc2[m][n] = zero;

  for (int kk = 0; kk < 12; ++kk) {
    frag_t A[4], Bv[6];
    int kb2 = (kk * 32 + (lane >> 4) * 8) * 2;
#pragma unroll
    for (int m = 0; m < 4; ++m) {
      int row = m * 16 + (lane & 15);
      int byte = row * 768 + kb2;
      byte ^= (row & 7) << 4;
      A[m] = *(const frag_t*)(tile + byte);
    }
    const unsigned short* bp_ = pWp + ((size_t)(kk * 24 + wv * 6) * 64 + lane) * 8;
#pragma unroll
    for (int n = 0; n < 6; ++n) Bv[n] = *(const frag_t*)(bp_ + (size_t)n * 64 * 8);
#pragma unroll
    for (int m = 0; m < 4; ++m)
#pragma unroll
      for (int n = 0; n < 6; ++n) acc2[m][n] = mfma_bf16(A[m], Bv[n], acc2[m][n]);
  }

  // epilogue2: out = acc2 + bp
#pragma unroll
  for (int m = 0; m < 4; ++m) {
#pragma unroll
    for (int n = 0; n < 6; ++n) {
      int col = wcol + n * 16 + (lane & 15);
      float bpv = bp_l[col];
#pragma unroll
      for (int r = 0; r < 4; ++r) {
        int row = m * 16 + (lane >> 4) * 4 + r;
        out[(size_t)(R0 + row) * C_ + col] = acc2[m][n][r] + bpv;
      }
    }
  }
}

extern "C" void kernel_launch(void* const* d_in, const int* in_sizes, int n_in,
                              void* d_out, int out_size, void* d_ws, size_t ws_size,
                              hipStream_t stream) {
  const float* x      = (const float*)d_in[0];
  const float* w_qkv  = (const float*)d_in[1];
  const float* b_qkv  = (const float*)d_in[2];
  const float* w_proj = (const float*)d_in[3];
  const float* b_proj = (const float*)d_in[4];
  float* out = (float*)d_out;

  // workspace: xsum[128*384 f] | cv[128*384 f] | pWv[147456 bf16] | pWp[147456 bf16]
  float* xsum = (float*)d_ws;
  float* cvp  = xsum + G_ * C_;
  unsigned short* pWv = (unsigned short*)(cvp + G_ * C_);
  unsigned short* pWp = pWv + C_ * C_;

  hipMemsetAsync(xsum, 0, G_ * C_ * sizeof(float), stream);
  k_pack<<<576, 64, 0, stream>>>(w_qkv, w_proj, pWv, pWp);
  k_xsum<<<G_ * SPLIT, C_, 0, stream>>>(x, xsum);
  k_cv<<<G_, C_, 0, stream>>>(xsum, w_qkv, b_qkv, cvp);
  k_fused<<<2048, 256, 0, stream>>>(x, pWv, pWp, cvp, b_qkv, b_proj, out);
}